// Round 3
// baseline (529.850 us; speedup 1.0000x reference)
//
#include <hip/hip_runtime.h>
#include <stdint.h>

#define E_N 600000
#define N_N 100000

typedef short short8  __attribute__((ext_vector_type(8)));
typedef short short8a __attribute__((ext_vector_type(8), may_alias));
typedef float floatx4 __attribute__((ext_vector_type(4)));
typedef unsigned int uintx4a __attribute__((ext_vector_type(4), may_alias));

static __device__ __forceinline__ unsigned short f2bf(float f){
  unsigned u = __builtin_bit_cast(unsigned, f);
  unsigned rnd = 0x7fffu + ((u >> 16) & 1u);
  return (unsigned short)((u + rnd) >> 16);
}
static __device__ __forceinline__ unsigned pack2(float a, float b){
  return (unsigned)f2bf(a) | ((unsigned)f2bf(b) << 16);
}

// ---- prep: W1 (384x128) -> w1t bf16 [col][k]; W2 (128x128) -> w2t bf16 [col][k]
__global__ void prep_weights(const float* __restrict__ W1, const float* __restrict__ W2,
                             unsigned short* __restrict__ w1t, unsigned short* __restrict__ w2t){
  int i = blockIdx.x * 256 + threadIdx.x;
  if (i < 384 * 128){
    int c = i / 384, k = i - c * 384;
    w1t[i] = f2bf(W1[k * 128 + c]);
  } else {
    int j = i - 384 * 128;            // grid sized exactly: j < 16384
    int c = j >> 7, k = j & 127;
    w2t[j] = f2bf(W2[k * 128 + c]);
  }
}

// ---- prep: copy nfeat -> output[1]; optionally nfeat f32 -> bf16 in ws
__global__ void prep_nfeat(const float* __restrict__ nf,
                           unsigned* __restrict__ nfbu,      // may be null
                           float* __restrict__ out2){
  const int total = N_N * 128 / 4;
  int stride = gridDim.x * blockDim.x;
  for (int i = blockIdx.x * blockDim.x + threadIdx.x; i < total; i += stride){
    float4 v = reinterpret_cast<const float4*>(nf)[i];
    reinterpret_cast<float4*>(out2)[i] = v;
    if (nfbu){
      nfbu[2 * i]     = pack2(v.x, v.y);
      nfbu[2 * i + 1] = pack2(v.z, v.w);
    }
  }
}

// ---- fused, operand-swapped: h^T = W1^T @ X^T ; y^T = W2^T @ h^T
// block = 256 = 4 waves, 32 edges/wave (2 col-frags of 16 edges)
template<bool USE_NFB, bool USE_WT>
__global__ __launch_bounds__(256) void fused_edge(
    const float* __restrict__ efeat,
    const int* __restrict__ src_idx, const int* __restrict__ dst_idx,
    const float* __restrict__ nfeat,
    const unsigned short* __restrict__ nfb,
    const float* __restrict__ W1f, const float* __restrict__ W2f,
    const unsigned short* __restrict__ w1t, const unsigned short* __restrict__ w2t,
    const float* __restrict__ b1, const float* __restrict__ b2,
    const float* __restrict__ lns, const float* __restrict__ lnb,
    float* __restrict__ out)
{
  // per-wave h tile: [edge(32)][chan(128) bf16] = 2048 dwords, XOR-swizzled
  __shared__ unsigned int hT[4][2048];

  const int tid  = threadIdx.x;
  const int w    = tid >> 6;
  const int lane = tid & 63;
  const int r    = lane & 15;     // A row (chan) / B col (edge)
  const int g    = lane >> 4;     // k-slot group; D row = 4g+q

  unsigned int* tile = &hT[w][0];
  const int sw = (r & 7) << 2;    // dword-space XOR swizzle for row r (and r+16)

  const int eb = blockIdx.x * 128 + w * 32;

  int er[2];
  #pragma unroll
  for (int e2 = 0; e2 < 2; ++e2){
    int e = eb + 16 * e2 + r;
    er[e2] = e < E_N ? e : (E_N - 1);
  }
  int gidx[2][2];                 // [seg][e2]
  #pragma unroll
  for (int e2 = 0; e2 < 2; ++e2){
    int si = src_idx[er[e2]];
    int di = dst_idx[er[e2]];
    si = si < 0 ? 0 : (si >= N_N ? N_N - 1 : si);
    di = di < 0 ? 0 : (di >= N_N ? N_N - 1 : di);
    gidx[0][e2] = si;
    gidx[1][e2] = di;
  }

  auto loadX_f32 = [&](const float* p) -> short8 {   // X^T B-frag from f32 row
    float4 v0 = reinterpret_cast<const float4*>(p)[0];
    float4 v1 = reinterpret_cast<const float4*>(p)[1];
    short8 t;
    t[0] = (short)f2bf(v0.x); t[1] = (short)f2bf(v0.y);
    t[2] = (short)f2bf(v0.z); t[3] = (short)f2bf(v0.w);
    t[4] = (short)f2bf(v1.x); t[5] = (short)f2bf(v1.y);
    t[6] = (short)f2bf(v1.z); t[7] = (short)f2bf(v1.w);
    return t;
  };
  auto loadW1 = [&](int mi, int kk) -> short8 {      // A-frag: W1^T row 16mi+r, k kk..kk+7
    if constexpr (USE_WT){
      return *reinterpret_cast<const short8a*>(w1t + (16 * mi + r) * 384 + kk);
    } else {
      short8 t;
      #pragma unroll
      for (int j = 0; j < 8; ++j) t[j] = (short)f2bf(W1f[(kk + j) * 128 + 16 * mi + r]);
      return t;
    }
  };
  auto loadW2 = [&](int mo, int kk) -> short8 {
    if constexpr (USE_WT){
      return *reinterpret_cast<const short8a*>(w2t + (16 * mo + r) * 128 + kk);
    } else {
      short8 t;
      #pragma unroll
      for (int j = 0; j < 8; ++j) t[j] = (short)f2bf(W2f[(kk + j) * 128 + 16 * mo + r]);
      return t;
    }
  };

  // ---- GEMM1: acc1[e2][mi] = h[chan 16mi+4g+q][edge 16e2+r]
  floatx4 acc1[2][8];
  #pragma unroll
  for (int e2 = 0; e2 < 2; ++e2)
    #pragma unroll
    for (int mi = 0; mi < 8; ++mi)
      acc1[e2][mi] = (floatx4){0.f, 0.f, 0.f, 0.f};

  #pragma unroll
  for (int kf = 0; kf < 12; ++kf){
    short8 x[2];
    #pragma unroll
    for (int e2 = 0; e2 < 2; ++e2){
      if (kf < 4){
        x[e2] = loadX_f32(efeat + (size_t)er[e2] * 128 + kf * 32 + 8 * g);
      } else if (kf < 8){
        if constexpr (USE_NFB)
          x[e2] = *reinterpret_cast<const short8a*>(nfb + (size_t)gidx[0][e2] * 128 + (kf - 4) * 32 + 8 * g);
        else
          x[e2] = loadX_f32(nfeat + (size_t)gidx[0][e2] * 128 + (kf - 4) * 32 + 8 * g);
      } else {
        if constexpr (USE_NFB)
          x[e2] = *reinterpret_cast<const short8a*>(nfb + (size_t)gidx[1][e2] * 128 + (kf - 8) * 32 + 8 * g);
        else
          x[e2] = loadX_f32(nfeat + (size_t)gidx[1][e2] * 128 + (kf - 8) * 32 + 8 * g);
      }
    }
    #pragma unroll
    for (int mi = 0; mi < 8; ++mi){
      short8 wf = loadW1(mi, kf * 32 + 8 * g);
      acc1[0][mi] = __builtin_amdgcn_mfma_f32_16x16x32_bf16(wf, x[0], acc1[0][mi], 0, 0, 0);
      acc1[1][mi] = __builtin_amdgcn_mfma_f32_16x16x32_bf16(wf, x[1], acc1[1][mi], 0, 0, 0);
    }
  }

  // ---- epilogue 1: +b1, silu, pack bf16 pairs, swizzled ds writes (wave-private)
  float4 b1v[8];
  #pragma unroll
  for (int mi = 0; mi < 8; ++mi)
    b1v[mi] = *reinterpret_cast<const float4*>(b1 + 16 * mi + 4 * g);

  #pragma unroll
  for (int e2 = 0; e2 < 2; ++e2){
    int base = (16 * e2 + r) * 64;
    #pragma unroll
    for (int mi = 0; mi < 8; ++mi){
      float v[4];
      #pragma unroll
      for (int q = 0; q < 4; ++q){
        float xx = acc1[e2][mi][q] + ((const float*)&b1v[mi])[q];
        v[q] = xx / (1.f + __expf(-xx));        // silu
      }
      int d0 = 8 * mi + 2 * g;
      tile[base + ((d0)     ^ sw)] = pack2(v[0], v[1]);
      tile[base + ((d0 + 1) ^ sw)] = pack2(v[2], v[3]);
    }
  }

  // ---- GEMM2: acc2[e2][mo] = y[chan 16mo+4g+q][edge 16e2+r]
  floatx4 acc2[2][8];
  #pragma unroll
  for (int e2 = 0; e2 < 2; ++e2)
    #pragma unroll
    for (int mo = 0; mo < 8; ++mo)
      acc2[e2][mo] = (floatx4){0.f, 0.f, 0.f, 0.f};

  #pragma unroll
  for (int ks = 0; ks < 4; ++ks){
    short8 hb[2];
    #pragma unroll
    for (int e2 = 0; e2 < 2; ++e2){
      uintx4a hv = *reinterpret_cast<const uintx4a*>(
          &tile[(16 * e2 + r) * 64 + ((16 * ks + 4 * g) ^ sw)]);
      hb[e2] = __builtin_bit_cast(short8, hv);
    }
    #pragma unroll
    for (int mo = 0; mo < 8; ++mo){
      short8 wf = loadW2(mo, ks * 32 + 8 * g);
      acc2[0][mo] = __builtin_amdgcn_mfma_f32_16x16x32_bf16(wf, hb[0], acc2[0][mo], 0, 0, 0);
      acc2[1][mo] = __builtin_amdgcn_mfma_f32_16x16x32_bf16(wf, hb[1], acc2[1][mo], 0, 0, 0);
    }
  }

  // ---- epilogue 2: +b2, LN (2 shuffles), *scale+bias, +efeat, float4 stores
  float4 b2v[8], lsv[8], lbv[8];
  #pragma unroll
  for (int mo = 0; mo < 8; ++mo){
    b2v[mo] = *reinterpret_cast<const float4*>(b2  + 16 * mo + 4 * g);
    lsv[mo] = *reinterpret_cast<const float4*>(lns + 16 * mo + 4 * g);
    lbv[mo] = *reinterpret_cast<const float4*>(lnb + 16 * mo + 4 * g);
  }

  #pragma unroll
  for (int e2 = 0; e2 < 2; ++e2){
    float yv[8][4];
    float s1 = 0.f, s2 = 0.f;
    #pragma unroll
    for (int mo = 0; mo < 8; ++mo){
      #pragma unroll
      for (int q = 0; q < 4; ++q){
        float v = acc2[e2][mo][q] + ((const float*)&b2v[mo])[q];
        yv[mo][q] = v;
        s1 += v; s2 += v * v;
      }
    }
    s1 += __shfl_xor(s1, 16); s2 += __shfl_xor(s2, 16);
    s1 += __shfl_xor(s1, 32); s2 += __shfl_xor(s2, 32);

    float mu   = s1 * (1.f / 128.f);
    float var  = s2 * (1.f / 128.f) - mu * mu;
    var = var > 0.f ? var : 0.f;
    float rstd = rsqrtf(var + 1e-5f);

    int e = eb + 16 * e2 + r;
    if (e < E_N){
      const float* ef = efeat + (size_t)e * 128;
      float*       op = out   + (size_t)e * 128;
      #pragma unroll
      for (int mo = 0; mo < 8; ++mo){
        float4 e4 = *reinterpret_cast<const float4*>(ef + 16 * mo + 4 * g);
        float4 o4;
        o4.x = (yv[mo][0] - mu) * rstd * ((const float*)&lsv[mo])[0] + ((const float*)&lbv[mo])[0] + e4.x;
        o4.y = (yv[mo][1] - mu) * rstd * ((const float*)&lsv[mo])[1] + ((const float*)&lbv[mo])[1] + e4.y;
        o4.z = (yv[mo][2] - mu) * rstd * ((const float*)&lsv[mo])[2] + ((const float*)&lbv[mo])[2] + e4.z;
        o4.w = (yv[mo][3] - mu) * rstd * ((const float*)&lsv[mo])[3] + ((const float*)&lbv[mo])[3] + e4.w;
        *reinterpret_cast<float4*>(op + 16 * mo + 4 * g) = o4;
      }
    }
  }
}

extern "C" void kernel_launch(void* const* d_in, const int* in_sizes, int n_in,
                              void* d_out, int out_size, void* d_ws, size_t ws_size,
                              hipStream_t stream){
  const float* efeat = (const float*)d_in[0];
  const float* nfeat = (const float*)d_in[1];
  const int*   srci  = (const int*)d_in[2];
  const int*   dsti  = (const int*)d_in[3];
  const float* W1    = (const float*)d_in[4];
  const float* b1    = (const float*)d_in[5];
  const float* W2    = (const float*)d_in[6];
  const float* b2    = (const float*)d_in[7];
  const float* lns   = (const float*)d_in[8];
  const float* lnb   = (const float*)d_in[9];
  float* out = (float*)d_out;

  const size_t NEED_W   = (size_t)(384 * 128 + 128 * 128) * 2;   // 131,072 B
  const size_t NEED_NFB = (size_t)N_N * 128 * 2;                 // 25,600,000 B
  const bool wt_ok  = ws_size >= NEED_W;
  const bool nfb_ok = ws_size >= NEED_W + NEED_NFB;

  char* ws = (char*)d_ws;
  unsigned short* w1t = wt_ok  ? (unsigned short*)ws : nullptr;
  unsigned short* w2t = wt_ok  ? w1t + 384 * 128 : nullptr;
  unsigned short* nfb = nfb_ok ? (unsigned short*)(ws + NEED_W) : nullptr;

  if (wt_ok)
    prep_weights<<<(384 * 128 + 128 * 128) / 256, 256, 0, stream>>>(W1, W2, w1t, w2t);
  prep_nfeat<<<2048, 256, 0, stream>>>(nfeat, (unsigned*)nfb, out + (size_t)E_N * 128);

  int blocks = (E_N + 127) / 128;
  if (nfb_ok)
    fused_edge<true , true ><<<blocks, 256, 0, stream>>>(efeat, srci, dsti, nfeat, nfb,
                                                         W1, W2, w1t, w2t, b1, b2, lns, lnb, out);
  else if (wt_ok)
    fused_edge<false, true ><<<blocks, 256, 0, stream>>>(efeat, srci, dsti, nfeat, nfb,
                                                         W1, W2, w1t, w2t, b1, b2, lns, lnb, out);
  else
    fused_edge<false, false><<<blocks, 256, 0, stream>>>(efeat, srci, dsti, nfeat, nfb,
                                                         W1, W2, w1t, w2t, b1, b2, lns, lnb, out);
}

// Round 4
// 529.772 us; speedup vs baseline: 1.0001x; 1.0001x over previous
//
#include <hip/hip_runtime.h>
#include <stdint.h>

#define E_N 600000
#define N_N 100000

typedef short short8   __attribute__((ext_vector_type(8)));
typedef short short8a  __attribute__((ext_vector_type(8), may_alias));
typedef float floatx4  __attribute__((ext_vector_type(4)));
typedef float floatx2  __attribute__((ext_vector_type(2)));
typedef float floatx8a __attribute__((ext_vector_type(8), may_alias));
typedef unsigned int uintx2  __attribute__((ext_vector_type(2)));
typedef unsigned int uintx2a __attribute__((ext_vector_type(2), may_alias));
typedef unsigned int uintx4a __attribute__((ext_vector_type(4), may_alias));
typedef __bf16 bf16x2 __attribute__((ext_vector_type(2)));
typedef __bf16 bf16x4 __attribute__((ext_vector_type(4)));
typedef __bf16 bf16x8 __attribute__((ext_vector_type(8)));

static __device__ __forceinline__ unsigned short f2bf(float f){
  unsigned u = __builtin_bit_cast(unsigned, f);
  unsigned rnd = 0x7fffu + ((u >> 16) & 1u);
  return (unsigned short)((u + rnd) >> 16);
}
static __device__ __forceinline__ unsigned pk2(float a, float b){
  floatx2 f; f[0] = a; f[1] = b;
  return __builtin_bit_cast(unsigned, __builtin_convertvector(f, bf16x2));
}

// ---- prep: W1 (384x128) -> w1t bf16 [col][k]; W2 (128x128) -> w2t bf16 [col][k]
__global__ void prep_weights(const float* __restrict__ W1, const float* __restrict__ W2,
                             unsigned short* __restrict__ w1t, unsigned short* __restrict__ w2t){
  int i = blockIdx.x * 256 + threadIdx.x;
  if (i < 384 * 128){
    int c = i / 384, k = i - c * 384;
    w1t[i] = f2bf(W1[k * 128 + c]);
  } else {
    int j = i - 384 * 128;            // grid sized exactly: j < 16384
    int c = j >> 7, k = j & 127;
    w2t[j] = f2bf(W2[k * 128 + c]);
  }
}

// ---- prep: copy nfeat -> output[1]; optionally nfeat f32 -> bf16 in ws
__global__ void prep_nfeat(const float* __restrict__ nf,
                           unsigned* __restrict__ nfbu,      // may be null
                           float* __restrict__ out2){
  const int total = N_N * 128 / 4;
  int stride = gridDim.x * blockDim.x;
  for (int i = blockIdx.x * blockDim.x + threadIdx.x; i < total; i += stride){
    float4 v = reinterpret_cast<const float4*>(nf)[i];
    reinterpret_cast<float4*>(out2)[i] = v;
    if (nfbu){
      nfbu[2 * i]     = pk2(v.x, v.y);
      nfbu[2 * i + 1] = pk2(v.z, v.w);
    }
  }
}

// ---- fused, operand-swapped: h^T = W1^T @ X^T ; y^T = W2^T @ h^T
// block = 256 = 4 waves, 32 edges/wave (2 col-frags of 16 edges)
template<bool USE_NFB, bool USE_WT>
__global__ __launch_bounds__(256, 4) void fused_edge(
    const float* __restrict__ efeat,
    const int* __restrict__ src_idx, const int* __restrict__ dst_idx,
    const float* __restrict__ nfeat,
    const unsigned short* __restrict__ nfb,
    const float* __restrict__ W1f, const float* __restrict__ W2f,
    const unsigned short* __restrict__ w1t, const unsigned short* __restrict__ w2t,
    const float* __restrict__ b1, const float* __restrict__ b2,
    const float* __restrict__ lns, const float* __restrict__ lnb,
    float* __restrict__ out)
{
  // per-wave h tile: [edge(32)][chan(128) bf16] = 2048 dwords, XOR-swizzled
  __shared__ unsigned int hT[4][2048];
  // block-shared biases: [0:128)=b1 [128:256)=b2 [256:384)=ln_scale [384:512)=ln_bias
  __shared__ float cmisc[512];

  const int tid  = threadIdx.x;
  const int w    = tid >> 6;
  const int lane = tid & 63;
  const int r    = lane & 15;     // A row (chan) / B col (edge)
  const int g    = lane >> 4;     // k-slot group; D row = 4g+q

  cmisc[tid]       = tid < 128 ? b1[tid]  : b2[tid - 128];
  cmisc[tid + 256] = tid < 128 ? lns[tid] : lnb[tid - 128];
  __syncthreads();

  unsigned int* tile = &hT[w][0];
  const int sw = (r & 7) << 2;    // dword-space XOR swizzle for row r (and r+16)

  const int eb = blockIdx.x * 128 + w * 32;

  int er[2];
  #pragma unroll
  for (int e2 = 0; e2 < 2; ++e2){
    int e = eb + 16 * e2 + r;
    er[e2] = e < E_N ? e : (E_N - 1);
  }
  int gidx[2][2];                 // [seg][e2]
  #pragma unroll
  for (int e2 = 0; e2 < 2; ++e2){
    int si = src_idx[er[e2]];
    int di = dst_idx[er[e2]];
    si = si < 0 ? 0 : (si >= N_N ? N_N - 1 : si);
    di = di < 0 ? 0 : (di >= N_N ? N_N - 1 : di);
    gidx[0][e2] = si;
    gidx[1][e2] = di;
  }

  auto loadX_f32 = [&](const float* p) -> short8 {   // 8 f32 -> bf16x8 (4 cvt_pk)
    floatx8a f = *reinterpret_cast<const floatx8a*>(p);
    return __builtin_bit_cast(short8, __builtin_convertvector(f, bf16x8));
  };
  auto loadW1 = [&](int mi, int kk) -> short8 {      // A-frag: W1^T row 16mi+r, k kk..kk+7
    if constexpr (USE_WT){
      return *reinterpret_cast<const short8a*>(w1t + (16 * mi + r) * 384 + kk);
    } else {
      short8 t;
      #pragma unroll
      for (int j = 0; j < 8; ++j) t[j] = (short)f2bf(W1f[(kk + j) * 128 + 16 * mi + r]);
      return t;
    }
  };
  auto loadW2 = [&](int mo, int kk) -> short8 {
    if constexpr (USE_WT){
      return *reinterpret_cast<const short8a*>(w2t + (16 * mo + r) * 128 + kk);
    } else {
      short8 t;
      #pragma unroll
      for (int j = 0; j < 8; ++j) t[j] = (short)f2bf(W2f[(kk + j) * 128 + 16 * mo + r]);
      return t;
    }
  };

  // ---- GEMM1: acc1[e2][mi] = h[chan 16mi+4g+q][edge 16e2+r]
  floatx4 acc1[2][8];
  #pragma unroll
  for (int e2 = 0; e2 < 2; ++e2)
    #pragma unroll
    for (int mi = 0; mi < 8; ++mi)
      acc1[e2][mi] = (floatx4){0.f, 0.f, 0.f, 0.f};

  #pragma unroll
  for (int kf = 0; kf < 12; ++kf){
    short8 x[2];
    #pragma unroll
    for (int e2 = 0; e2 < 2; ++e2){
      if (kf < 4){
        x[e2] = loadX_f32(efeat + (size_t)er[e2] * 128 + kf * 32 + 8 * g);
      } else if (kf < 8){
        if constexpr (USE_NFB)
          x[e2] = *reinterpret_cast<const short8a*>(nfb + (size_t)gidx[0][e2] * 128 + (kf - 4) * 32 + 8 * g);
        else
          x[e2] = loadX_f32(nfeat + (size_t)gidx[0][e2] * 128 + (kf - 4) * 32 + 8 * g);
      } else {
        if constexpr (USE_NFB)
          x[e2] = *reinterpret_cast<const short8a*>(nfb + (size_t)gidx[1][e2] * 128 + (kf - 8) * 32 + 8 * g);
        else
          x[e2] = loadX_f32(nfeat + (size_t)gidx[1][e2] * 128 + (kf - 8) * 32 + 8 * g);
      }
    }
    #pragma unroll
    for (int mi = 0; mi < 8; ++mi){
      short8 wf = loadW1(mi, kf * 32 + 8 * g);
      acc1[0][mi] = __builtin_amdgcn_mfma_f32_16x16x32_bf16(wf, x[0], acc1[0][mi], 0, 0, 0);
      acc1[1][mi] = __builtin_amdgcn_mfma_f32_16x16x32_bf16(wf, x[1], acc1[1][mi], 0, 0, 0);
    }
  }

  // ---- epilogue 1: +b1, silu, pack bf16x4, one ds_write_b64 per (e2,mi)
  #pragma unroll
  for (int e2 = 0; e2 < 2; ++e2){
    int base = (16 * e2 + r) * 64;
    #pragma unroll
    for (int mi = 0; mi < 8; ++mi){
      floatx4 bb = *reinterpret_cast<const floatx4*>(&cmisc[16 * mi + 4 * g]);
      floatx4 vv;
      #pragma unroll
      for (int q = 0; q < 4; ++q){
        float xx = acc1[e2][mi][q] + bb[q];
        vv[q] = xx * __builtin_amdgcn_rcpf(1.f + __expf(-xx));   // silu
      }
      uintx2 pk = __builtin_bit_cast(uintx2, __builtin_convertvector(vv, bf16x4));
      int d0 = 8 * mi + 2 * g;                                   // even; sw has no bits 0-1
      *reinterpret_cast<uintx2a*>(&tile[base + (d0 ^ sw)]) = pk;
    }
  }

  // ---- GEMM2 + epilogue, split per e2 (acc2 = 32 VGPR, not 64)
  #pragma unroll
  for (int e2 = 0; e2 < 2; ++e2){
    floatx4 acc2[8];
    #pragma unroll
    for (int mo = 0; mo < 8; ++mo)
      acc2[mo] = (floatx4){0.f, 0.f, 0.f, 0.f};

    const int base = (16 * e2 + r) * 64;
    #pragma unroll
    for (int ks = 0; ks < 4; ++ks){
      uintx4a hv = *reinterpret_cast<const uintx4a*>(&tile[base + ((16 * ks + 4 * g) ^ sw)]);
      short8 hb = __builtin_bit_cast(short8, hv);
      #pragma unroll
      for (int mo = 0; mo < 8; ++mo){
        short8 wf = loadW2(mo, ks * 32 + 8 * g);
        acc2[mo] = __builtin_amdgcn_mfma_f32_16x16x32_bf16(wf, hb, acc2[mo], 0, 0, 0);
      }
    }

    // +b2, LN stats (2 shuffles), then normalize + residual + float4 store
    float s1 = 0.f, s2 = 0.f;
    #pragma unroll
    for (int mo = 0; mo < 8; ++mo){
      floatx4 bb = *reinterpret_cast<const floatx4*>(&cmisc[128 + 16 * mo + 4 * g]);
      #pragma unroll
      for (int q = 0; q < 4; ++q){
        float v = acc2[mo][q] + bb[q];
        s1 += v; s2 += v * v;
      }
    }
    s1 += __shfl_xor(s1, 16); s2 += __shfl_xor(s2, 16);
    s1 += __shfl_xor(s1, 32); s2 += __shfl_xor(s2, 32);

    float mu   = s1 * (1.f / 128.f);
    float var  = s2 * (1.f / 128.f) - mu * mu;
    var = var > 0.f ? var : 0.f;
    float rstd = __builtin_amdgcn_rsqf(var + 1e-5f);

    int e = eb + 16 * e2 + r;
    if (e < E_N){
      const float* ef = efeat + (size_t)e * 128;
      float*       op = out   + (size_t)e * 128;
      #pragma unroll
      for (int mo = 0; mo < 8; ++mo){
        int c = 16 * mo + 4 * g;
        floatx4 bb = *reinterpret_cast<const floatx4*>(&cmisc[128 + c]);
        floatx4 ls = *reinterpret_cast<const floatx4*>(&cmisc[256 + c]);
        floatx4 lb = *reinterpret_cast<const floatx4*>(&cmisc[384 + c]);
        floatx4 e4 = *reinterpret_cast<const floatx4*>(ef + c);
        floatx4 o4;
        #pragma unroll
        for (int q = 0; q < 4; ++q)
          o4[q] = (acc2[mo][q] + bb[q] - mu) * rstd * ls[q] + lb[q] + e4[q];
        *reinterpret_cast<floatx4*>(op + c) = o4;
      }
    }
  }
}

extern "C" void kernel_launch(void* const* d_in, const int* in_sizes, int n_in,
                              void* d_out, int out_size, void* d_ws, size_t ws_size,
                              hipStream_t stream){
  const float* efeat = (const float*)d_in[0];
  const float* nfeat = (const float*)d_in[1];
  const int*   srci  = (const int*)d_in[2];
  const int*   dsti  = (const int*)d_in[3];
  const float* W1    = (const float*)d_in[4];
  const float* b1    = (const float*)d_in[5];
  const float* W2    = (const float*)d_in[6];
  const float* b2    = (const float*)d_in[7];
  const float* lns   = (const float*)d_in[8];
  const float* lnb   = (const float*)d_in[9];
  float* out = (float*)d_out;

  const size_t NEED_W   = (size_t)(384 * 128 + 128 * 128) * 2;   // 131,072 B
  const size_t NEED_NFB = (size_t)N_N * 128 * 2;                 // 25,600,000 B
  const bool wt_ok  = ws_size >= NEED_W;
  const bool nfb_ok = ws_size >= NEED_W + NEED_NFB;

  char* ws = (char*)d_ws;
  unsigned short* w1t = wt_ok  ? (unsigned short*)ws : nullptr;
  unsigned short* w2t = wt_ok  ? w1t + 384 * 128 : nullptr;
  unsigned short* nfb = nfb_ok ? (unsigned short*)(ws + NEED_W) : nullptr;

  if (wt_ok)
    prep_weights<<<(384 * 128 + 128 * 128) / 256, 256, 0, stream>>>(W1, W2, w1t, w2t);
  prep_nfeat<<<2048, 256, 0, stream>>>(nfeat, (unsigned*)nfb, out + (size_t)E_N * 128);

  int blocks = (E_N + 127) / 128;
  if (nfb_ok)
    fused_edge<true , true ><<<blocks, 256, 0, stream>>>(efeat, srci, dsti, nfeat, nfb,
                                                         W1, W2, w1t, w2t, b1, b2, lns, lnb, out);
  else if (wt_ok)
    fused_edge<false, true ><<<blocks, 256, 0, stream>>>(efeat, srci, dsti, nfeat, nfb,
                                                         W1, W2, w1t, w2t, b1, b2, lns, lnb, out);
  else
    fused_edge<false, false><<<blocks, 256, 0, stream>>>(efeat, srci, dsti, nfeat, nfb,
                                                         W1, W2, w1t, w2t, b1, b2, lns, lnb, out);
}

// Round 5
// 259.369 us; speedup vs baseline: 2.0428x; 2.0425x over previous
//
#include <hip/hip_runtime.h>
#include <stdint.h>

#define E_N 600000
#define N_N 100000

typedef short short8   __attribute__((ext_vector_type(8)));
typedef short short8a  __attribute__((ext_vector_type(8), may_alias));
typedef float floatx4  __attribute__((ext_vector_type(4)));
typedef float floatx2  __attribute__((ext_vector_type(2)));
typedef float floatx4a __attribute__((ext_vector_type(4), may_alias));
typedef float floatx8a __attribute__((ext_vector_type(8), may_alias));
typedef unsigned int uintx2  __attribute__((ext_vector_type(2)));
typedef unsigned int uintx2a __attribute__((ext_vector_type(2), may_alias));
typedef unsigned int uintx4a __attribute__((ext_vector_type(4), may_alias));
typedef __bf16 bf16x4 __attribute__((ext_vector_type(4)));
typedef __bf16 bf16x8 __attribute__((ext_vector_type(8)));

static __device__ __forceinline__ unsigned short f2bf(float f){
  unsigned u = __builtin_bit_cast(unsigned, f);
  unsigned rnd = 0x7fffu + ((u >> 16) & 1u);
  return (unsigned short)((u + rnd) >> 16);
}
static __device__ __forceinline__ unsigned pk2(float a, float b){
  floatx2 f; f[0] = a; f[1] = b;
  typedef __bf16 bf16x2 __attribute__((ext_vector_type(2)));
  return __builtin_bit_cast(unsigned, __builtin_convertvector(f, bf16x2));
}

// ---- prep: weights -> bf16, [row][k] layout, PRE-SWIZZLED in dword space:
//   dst_dw = row*(K/2) + ((k>>1) ^ ((row&7)<<2)), halfword k&1
__global__ void prep_weights(const float* __restrict__ W1, const float* __restrict__ W2,
                             unsigned short* __restrict__ w1s, unsigned short* __restrict__ w2s){
  int i = blockIdx.x * 256 + threadIdx.x;
  if (i < 384 * 128){
    int c = i / 384, k = i - c * 384;
    int dw = c * 192 + ((k >> 1) ^ ((c & 7) << 2));
    w1s[dw * 2 + (k & 1)] = f2bf(W1[k * 128 + c]);
  } else {
    int j = i - 384 * 128;            // grid sized exactly: j < 16384
    int c = j >> 7, k = j & 127;
    int dw = c * 64 + ((k >> 1) ^ ((c & 7) << 2));
    w2s[dw * 2 + (k & 1)] = f2bf(W2[k * 128 + c]);
  }
}

// ---- prep: copy nfeat -> output[1]; nfeat f32 -> bf16 in ws
__global__ void prep_nfeat(const float* __restrict__ nf,
                           unsigned* __restrict__ nfbu,
                           float* __restrict__ out2){
  const int total = N_N * 128 / 4;
  int stride = gridDim.x * blockDim.x;
  for (int i = blockIdx.x * blockDim.x + threadIdx.x; i < total; i += stride){
    float4 v = reinterpret_cast<const float4*>(nf)[i];
    reinterpret_cast<float4*>(out2)[i] = v;
    nfbu[2 * i]     = pk2(v.x, v.y);
    nfbu[2 * i + 1] = pk2(v.z, v.w);
  }
}

static __device__ __forceinline__ void glds16(void* lds, const void* g){
  __builtin_amdgcn_global_load_lds((const __attribute__((address_space(1))) unsigned int*)g,
                                   (__attribute__((address_space(3))) unsigned int*)lds,
                                   16, 0, 0);
}

// ---- fused, operand-swapped: h^T = W1^T X^T ; y^T = W2^T h^T
// 512 thr = 8 waves, 64 edges/wave (4 e-frags of 16), weights staged in LDS.
__global__ __launch_bounds__(512, 2) void fused_edge(
    const float* __restrict__ efeat,
    const int* __restrict__ src_idx, const int* __restrict__ dst_idx,
    const unsigned short* __restrict__ nfb,
    const unsigned short* __restrict__ w1s, const unsigned short* __restrict__ w2s,
    const float* __restrict__ b1, const float* __restrict__ b2,
    const float* __restrict__ lns, const float* __restrict__ lnb,
    float* __restrict__ out)
{
  // [0, 98304)        : W1 swizzled bf16 (GEMM1), then W2 restaged in [0,32768) (GEMM2)
  // [98304, 131072)   : per-wave h tile, 4 KB each ([16 edge][64 dw], swizzled)
  // [131072, 133120)  : biases: b1 | b2 | ln_scale | ln_bias (128 f32 each)
  __shared__ __align__(16) unsigned char smem[133120];
  unsigned int* wlds  = (unsigned int*)smem;
  float*        cmisc = (float*)(smem + 131072);

  const int tid  = threadIdx.x;
  const int w    = tid >> 6;
  const int lane = tid & 63;
  const int r    = lane & 15;     // A row (chan) / B col (edge)
  const int g    = lane >> 4;     // k-group; D row = 4g+q
  const int sw8  = (r & 7) << 2;  // dword XOR swizzle

  unsigned int* tile = (unsigned int*)(smem + 98304 + w * 4096);

  // stage W1 (96 KB) contiguously; source is pre-swizzled so LDS ends up swizzled
  #pragma unroll
  for (int rnd = 0; rnd < 12; ++rnd){
    int off = rnd * 8192 + tid * 16;
    glds16(smem + off, (const unsigned char*)w1s + off);
  }
  cmisc[tid] = tid < 128 ? b1[tid] : tid < 256 ? b2[tid - 128]
             : tid < 384 ? lns[tid - 256] : lnb[tid - 384];

  const int eb = blockIdx.x * 512 + w * 64;

  int er[4];
  #pragma unroll
  for (int e2 = 0; e2 < 4; ++e2){
    int e = eb + 16 * e2 + r;
    er[e2] = e < E_N ? e : (E_N - 1);
  }
  int gidx[2][4];
  #pragma unroll
  for (int e2 = 0; e2 < 4; ++e2){
    int si = src_idx[er[e2]];
    int di = dst_idx[er[e2]];
    si = si < 0 ? 0 : (si >= N_N ? N_N - 1 : si);
    di = di < 0 ? 0 : (di >= N_N ? N_N - 1 : di);
    gidx[0][e2] = si;
    gidx[1][e2] = di;
  }

  __syncthreads();   // W1 + cmisc ready

  auto loadX_f32 = [&](const float* p) -> short8 {
    floatx8a f = *reinterpret_cast<const floatx8a*>(p);
    return __builtin_bit_cast(short8, __builtin_convertvector(f, bf16x8));
  };
  // W1 A-frag from LDS: row 16mi+r, k = kf*32+8g .. +7  (b128, bank-balanced)
  auto loadW1L = [&](int mi, int kf) -> short8 {
    uintx4a v = *reinterpret_cast<const uintx4a*>(
        &wlds[(16 * mi + r) * 192 + ((kf * 16 + 4 * g) ^ sw8)]);
    return __builtin_bit_cast(short8, v);
  };
  auto loadW2L = [&](int mo, int ks) -> short8 {
    uintx4a v = *reinterpret_cast<const uintx4a*>(
        &wlds[(16 * mo + r) * 64 + ((ks * 16 + 4 * g) ^ sw8)]);
    return __builtin_bit_cast(short8, v);
  };

  // ---- GEMM1: acc1[e2][mi] = h[chan 16mi+4g+q][edge 16e2+r]
  floatx4 acc1[4][8];
  #pragma unroll
  for (int e2 = 0; e2 < 4; ++e2)
    #pragma unroll
    for (int mi = 0; mi < 8; ++mi)
      acc1[e2][mi] = (floatx4){0.f, 0.f, 0.f, 0.f};

  #pragma unroll
  for (int kf = 0; kf < 12; ++kf){
    short8 x[4];
    #pragma unroll
    for (int e2 = 0; e2 < 4; ++e2){
      if (kf < 4)
        x[e2] = loadX_f32(efeat + (size_t)er[e2] * 128 + kf * 32 + 8 * g);
      else if (kf < 8)
        x[e2] = *reinterpret_cast<const short8a*>(nfb + (size_t)gidx[0][e2] * 128 + (kf - 4) * 32 + 8 * g);
      else
        x[e2] = *reinterpret_cast<const short8a*>(nfb + (size_t)gidx[1][e2] * 128 + (kf - 8) * 32 + 8 * g);
    }
    #pragma unroll
    for (int mi = 0; mi < 8; ++mi){
      short8 wf = loadW1L(mi, kf);
      #pragma unroll
      for (int e2 = 0; e2 < 4; ++e2)
        acc1[e2][mi] = __builtin_amdgcn_mfma_f32_16x16x32_bf16(wf, x[e2], acc1[e2][mi], 0, 0, 0);
    }
  }

  __syncthreads();   // everyone done reading W1
  // restage W2 (32 KB) over the W1 region
  #pragma unroll
  for (int rnd = 0; rnd < 4; ++rnd){
    int off = rnd * 8192 + tid * 16;
    glds16(smem + off, (const unsigned char*)w2s + off);
  }

  // epilogue-1 for e2=0 overlaps the staging latency (hT region is untouched)
  auto epi1 = [&](int e2){
    #pragma unroll
    for (int mi = 0; mi < 8; ++mi){
      floatx4 bb = *reinterpret_cast<const floatx4a*>(&cmisc[16 * mi + 4 * g]);
      floatx4 vv;
      #pragma unroll
      for (int q = 0; q < 4; ++q){
        float xx = acc1[e2][mi][q] + bb[q];
        vv[q] = xx * __builtin_amdgcn_rcpf(1.f + __expf(-xx));   // silu
      }
      uintx2 pk = __builtin_bit_cast(uintx2, __builtin_convertvector(vv, bf16x4));
      *reinterpret_cast<uintx2a*>(&tile[r * 64 + ((8 * mi + 2 * g) ^ sw8)]) = pk;
    }
  };
  epi1(0);

  __syncthreads();   // W2 ready

  // ---- per e-frag: GEMM2 + LN epilogue (single 4 KB tile reused sequentially)
  #pragma unroll
  for (int e2 = 0; e2 < 4; ++e2){
    if (e2 > 0) epi1(e2);

    floatx4 acc2[8];
    #pragma unroll
    for (int mo = 0; mo < 8; ++mo)
      acc2[mo] = (floatx4){0.f, 0.f, 0.f, 0.f};

    #pragma unroll
    for (int ks = 0; ks < 4; ++ks){
      uintx4a hv = *reinterpret_cast<const uintx4a*>(&tile[r * 64 + ((ks * 16 + 4 * g) ^ sw8)]);
      short8 hb = __builtin_bit_cast(short8, hv);
      #pragma unroll
      for (int mo = 0; mo < 8; ++mo){
        short8 wf = loadW2L(mo, ks);
        acc2[mo] = __builtin_amdgcn_mfma_f32_16x16x32_bf16(wf, hb, acc2[mo], 0, 0, 0);
      }
    }

    float s1 = 0.f, s2 = 0.f;
    #pragma unroll
    for (int mo = 0; mo < 8; ++mo){
      floatx4 bb = *reinterpret_cast<const floatx4a*>(&cmisc[128 + 16 * mo + 4 * g]);
      #pragma unroll
      for (int q = 0; q < 4; ++q){
        float v = acc2[mo][q] + bb[q];
        s1 += v; s2 += v * v;
      }
    }
    s1 += __shfl_xor(s1, 16); s2 += __shfl_xor(s2, 16);
    s1 += __shfl_xor(s1, 32); s2 += __shfl_xor(s2, 32);

    float mu   = s1 * (1.f / 128.f);
    float var  = s2 * (1.f / 128.f) - mu * mu;
    var = var > 0.f ? var : 0.f;
    float rstd = __builtin_amdgcn_rsqf(var + 1e-5f);

    int e = eb + 16 * e2 + r;
    if (e < E_N){
      const float* ef = efeat + (size_t)e * 128;
      float*       op = out   + (size_t)e * 128;
      #pragma unroll
      for (int mo = 0; mo < 8; ++mo){
        int c = 16 * mo + 4 * g;
        floatx4 bb = *reinterpret_cast<const floatx4a*>(&cmisc[128 + c]);
        floatx4 ls = *reinterpret_cast<const floatx4a*>(&cmisc[256 + c]);
        floatx4 lb = *reinterpret_cast<const floatx4a*>(&cmisc[384 + c]);
        floatx4 e4 = *reinterpret_cast<const floatx4a*>(ef + c);
        floatx4 o4;
        #pragma unroll
        for (int q = 0; q < 4; ++q)
          o4[q] = (acc2[mo][q] + bb[q] - mu) * rstd * ls[q] + lb[q] + e4[q];
        *reinterpret_cast<floatx4a*>(op + c) = o4;
      }
    }
  }
}

extern "C" void kernel_launch(void* const* d_in, const int* in_sizes, int n_in,
                              void* d_out, int out_size, void* d_ws, size_t ws_size,
                              hipStream_t stream){
  const float* efeat = (const float*)d_in[0];
  const float* nfeat = (const float*)d_in[1];
  const int*   srci  = (const int*)d_in[2];
  const int*   dsti  = (const int*)d_in[3];
  const float* W1    = (const float*)d_in[4];
  const float* b1    = (const float*)d_in[5];
  const float* W2    = (const float*)d_in[6];
  const float* b2    = (const float*)d_in[7];
  const float* lns   = (const float*)d_in[8];
  const float* lnb   = (const float*)d_in[9];
  float* out = (float*)d_out;

  char* ws = (char*)d_ws;
  unsigned short* w1s = (unsigned short*)ws;               // 98,304 B (swizzled)
  unsigned short* w2s = (unsigned short*)(ws + 98304);     // 32,768 B (swizzled)
  unsigned short* nfb = (unsigned short*)(ws + 131072);    // 25,600,000 B

  prep_weights<<<(384 * 128 + 128 * 128) / 256, 256, 0, stream>>>(W1, W2, w1s, w2s);
  prep_nfeat<<<2048, 256, 0, stream>>>(nfeat, (unsigned*)nfb, out + (size_t)E_N * 128);

  int blocks = (E_N + 511) / 512;   // 1172
  fused_edge<<<blocks, 512, 0, stream>>>(efeat, srci, dsti, nfb, w1s, w2s,
                                         b1, b2, lns, lnb, out);
}